// Round 1
// 990.565 us; speedup vs baseline: 2.4235x; 2.4235x over previous
//
#include <hip/hip_runtime.h>
#include <stdint.h>

// Problem constants
#define T_TOK 16384
#define DH    1024
#define FF    2048
#define NE    8
#define NC    4096          // 2F
#define PADROWS 33792       // 264 * 128  (T*K rounded up with per-expert 128-padding)

typedef __attribute__((ext_vector_type(8))) __bf16 bf16x8;
typedef __attribute__((ext_vector_type(4))) float  f32x4;

__device__ __forceinline__ float bf2f(unsigned short s) {
  unsigned int u = ((unsigned int)s) << 16;
  return __builtin_bit_cast(float, u);
}
__device__ __forceinline__ unsigned short f2bf(float f) {
  unsigned int u = __builtin_bit_cast(unsigned int, f);
  u += 0x7fffu + ((u >> 16) & 1u);          // RNE
  return (unsigned short)(u >> 16);
}

// async global->LDS, 16B per lane. Global src is PER-LANE; LDS dest is
// wave-uniform base + lane*16 (hardware-defined linear scatter).
__device__ __forceinline__ void gload_lds16(const void* g, void* l) {
  __builtin_amdgcn_global_load_lds(
      (__attribute__((address_space(1))) void*)(uintptr_t)g,
      (__attribute__((address_space(3))) void*)(uint32_t)(uintptr_t)l,
      16, 0, 0);
}

// interleaved column mapping: c'' in [0,4096) -> original gate_up column.
// group g = c''>>5; within: [0,16) -> gate f=g*16+wi, [16,32) -> up (orig 2048+f)
__device__ __forceinline__ int origc_gu(int c) {
  int g = c >> 5, wi = c & 31;
  return ((wi >> 4) << 11) | (g * 16 + (wi & 15));
}

// ---------------- fold kernels: W' = W + 2*A^T B^T, fp32 in -> bf16 out, TRANSPOSED [N][K] ----------------
__global__ void fold_gu_kernel(const float* __restrict__ Wg,   // [NE][DH][NC] fp32
                               const float* __restrict__ A,    // [NE][16][DH] fp32
                               const float* __restrict__ B,    // [NE][NC][16] fp32
                               unsigned short* __restrict__ Wf) // [NE][NC][DH] bf16, interleaved cols
{
  const int e = blockIdx.x, d0 = blockIdx.y * 64, c0 = blockIdx.z * 64;
  __shared__ float tile[64][65];
  __shared__ float Al[16][64];
  __shared__ float Bl[64][17];
  const int tid = threadIdx.x;
  for (int i = tid; i < 16 * 64; i += 256)
    Al[i >> 6][i & 63] = A[((size_t)e * 16 + (i >> 6)) * DH + d0 + (i & 63)];
  for (int i = tid; i < 64 * 16; i += 256) {
    int c = i >> 4, r = i & 15;
    Bl[c][r] = B[((size_t)e * NC + origc_gu(c0 + c)) * 16 + r];
  }
  __syncthreads();
  for (int pth = 0; pth < 16; pth++) {
    int idx = pth * 256 + tid;
    int dl = idx >> 6, cl = idx & 63;
    float v = Wg[((size_t)e * DH + d0 + dl) * NC + origc_gu(c0 + cl)];
    float sacc = 0.f;
#pragma unroll
    for (int r = 0; r < 16; r++) sacc += Al[r][dl] * Bl[cl][r];
    tile[dl][cl] = v + 2.f * sacc;
  }
  __syncthreads();
  for (int pth = 0; pth < 16; pth++) {
    int idx = pth * 256 + tid;
    int cl = idx >> 6, dl = idx & 63;
    Wf[((size_t)e * NC + c0 + cl) * DH + d0 + dl] = f2bf(tile[dl][cl]);
  }
}

__global__ void fold_dn_kernel(const float* __restrict__ Wd,   // [NE][FF][DH] fp32
                               const float* __restrict__ A,    // [NE][16][FF] fp32
                               const float* __restrict__ B,    // [NE][DH][16] fp32
                               unsigned short* __restrict__ Wf) // [NE][DH][FF] bf16
{
  const int e = blockIdx.x, f0 = blockIdx.y * 64, d0 = blockIdx.z * 64;
  __shared__ float tile[64][65];   // [f][d]
  __shared__ float Al[16][64];     // [r][f]
  __shared__ float Bl[64][17];     // [d][r]
  const int tid = threadIdx.x;
  for (int i = tid; i < 16 * 64; i += 256)
    Al[i >> 6][i & 63] = A[((size_t)e * 16 + (i >> 6)) * FF + f0 + (i & 63)];
  for (int i = tid; i < 64 * 16; i += 256) {
    int d = i >> 4, r = i & 15;
    Bl[d][r] = B[((size_t)e * DH + d0 + d) * 16 + r];
  }
  __syncthreads();
  for (int pth = 0; pth < 16; pth++) {
    int idx = pth * 256 + tid;
    int fl = idx >> 6, dl = idx & 63;
    float v = Wd[((size_t)e * FF + f0 + fl) * DH + d0 + dl];
    float sacc = 0.f;
#pragma unroll
    for (int r = 0; r < 16; r++) sacc += Al[r][fl] * Bl[dl][r];
    tile[fl][dl] = v + 2.f * sacc;
  }
  __syncthreads();
  for (int pth = 0; pth < 16; pth++) {
    int idx = pth * 256 + tid;
    int dl = idx >> 6, fl = idx & 63;
    Wf[((size_t)e * DH + d0 + dl) * FF + f0 + fl] = f2bf(tile[fl][dl]);
  }
}

// ---------------- X fp32 -> bf16 pre-convert (removes f2bf from gemm1 hot loop) ----------------
__global__ __launch_bounds__(256) void cvtx_kernel(const float* __restrict__ X,
                                                   unsigned short* __restrict__ Xbf)
{
  const size_t i = ((size_t)blockIdx.x * 256 + threadIdx.x) * 8;
  const float4 a = *(const float4*)&X[i];
  const float4 b = *(const float4*)&X[i + 4];
  uint4 o;
  o.x = (unsigned)f2bf(a.x) | ((unsigned)f2bf(a.y) << 16);
  o.y = (unsigned)f2bf(a.z) | ((unsigned)f2bf(a.w) << 16);
  o.z = (unsigned)f2bf(b.x) | ((unsigned)f2bf(b.y) << 16);
  o.w = (unsigned)f2bf(b.z) | ((unsigned)f2bf(b.w) << 16);
  *(uint4*)&Xbf[i] = o;
}

// ---------------- routing: logits -> top-2 -> normalized weights (all fp32) ----------------
__global__ __launch_bounds__(256) void route_kernel(
    const float* __restrict__ X,
    const float* __restrict__ GW,
    const float* __restrict__ GLD,
    int* __restrict__ tokE, float* __restrict__ tokW, int* __restrict__ counts)
{
  __shared__ float gc[NE * DH];
  __shared__ int bc[NE];
  const int tid = threadIdx.x;
  if (tid < NE) bc[tid] = 0;
  for (int i = tid; i < NE * DH; i += 256) gc[i] = GW[i] + GLD[i];
  __syncthreads();
  const int w = tid >> 6, lane = tid & 63;
  for (int it = 0; it < 8; it++) {
    const int t = blockIdx.x * 32 + w * 8 + it;
    float s[NE];
#pragma unroll
    for (int e = 0; e < NE; e++) s[e] = 0.f;
#pragma unroll
    for (int i = 0; i < 8; i++) {
      const int base = 2 * lane + 128 * i;
      const float2 xv = *(const float2*)&X[(size_t)t * DH + base];
#pragma unroll
      for (int e = 0; e < NE; e++) {
        float2 g2 = *(const float2*)&gc[e * DH + base];
        s[e] += xv.x * g2.x + xv.y * g2.y;
      }
    }
#pragma unroll
    for (int e = 0; e < NE; e++) {
#pragma unroll
      for (int off = 32; off > 0; off >>= 1) s[e] += __shfl_xor(s[e], off);
    }
    int e1 = 0; float l1 = s[0];
#pragma unroll
    for (int e = 1; e < NE; e++) { if (s[e] > l1) { l1 = s[e]; e1 = e; } }
    int e2i = 0; float l2 = -3.4e38f;
#pragma unroll
    for (int e = 0; e < NE; e++) { if (e != e1 && s[e] > l2) { l2 = s[e]; e2i = e; } }
    float r = __expf(l2 - l1);
    float w0 = 1.f / (1.f + r);
    if (lane == 0) {
      tokE[2 * t] = e1; tokE[2 * t + 1] = e2i;
      tokW[2 * t] = w0; tokW[2 * t + 1] = 1.f - w0;
      atomicAdd(&bc[e1], 1); atomicAdd(&bc[e2i], 1);
    }
  }
  __syncthreads();
  if (tid < NE) atomicAdd(&counts[tid], bc[tid]);
}

__global__ void offs_kernel(const int* __restrict__ counts, int* __restrict__ offs) {
  if (threadIdx.x == 0) {
    int run = 0;
#pragma unroll
    for (int e = 0; e < NE; e++) { offs[e] = run; run += (counts[e] + 127) & ~127; }
    offs[NE] = run;
  }
}

__global__ void scatter_kernel(const int* __restrict__ tokE,
                               const int* __restrict__ offs,
                               int* __restrict__ cursor,
                               int* __restrict__ posTok,
                               int* __restrict__ posOf)
{
  const int t = blockIdx.x * 256 + threadIdx.x;
  const int lane = threadIdx.x & 63;
#pragma unroll
  for (int k = 0; k < 2; k++) {
    const int e = tokE[2 * t + k];
    int p = 0;
#pragma unroll
    for (int ei = 0; ei < NE; ei++) {
      unsigned long long mask = __ballot(e == ei);
      if (mask) {
        int leader = __ffsll((unsigned long long)mask) - 1;
        int base = 0;
        if (lane == leader) base = atomicAdd(&cursor[ei], (int)__popcll(mask));
        base = __shfl(base, leader);
        if (e == ei)
          p = offs[ei] + base + (int)__popcll(mask & ((1ull << lane) - 1ull));
      }
    }
    if (p < 0) p = 0;
    if (p >= PADROWS) p = PADROWS - 1;
    posTok[p] = t;
    posOf[2 * t + k] = p;
  }
}

// ---------------- GEMM1 (m97 structure): H = silu/up( gather(Xbf) @ Wgu'' ) ----------------
// 128x128 tile, BK=32, 16KiB LDS, global_load_lds width-16 staging, 2 barriers/K-step.
__global__ __launch_bounds__(256) void gemm1_kernel(
    const unsigned short* __restrict__ Xbf,   // [T][DH] bf16
    const unsigned short* __restrict__ Wgu,   // [NE][NC][DH] bf16 transposed+interleaved
    const int* __restrict__ posTok,
    const int* __restrict__ offs,
    unsigned short* __restrict__ H)           // [PADROWS][FF] bf16
{
  __shared__ __align__(16) unsigned short As[128 * 32];   // [row][k] 8 KiB
  __shared__ __align__(16) unsigned short Bs[128 * 32];   // [col][k] 8 KiB
  const int n0 = blockIdx.x * 128;
  const int row0 = blockIdx.y * 128;
  if (row0 >= offs[NE]) return;
  int e = 0;
#pragma unroll
  for (int i = 1; i < NE; i++) e += (row0 >= offs[i]) ? 1 : 0;
  const unsigned short* Wb = Wgu + (size_t)e * NC * DH;

  const int tid = threadIdx.x;
  const int lane = tid & 63;
  const int w = tid >> 6;
  const int wm = w >> 1, wn = w & 1;
  const int l15 = lane & 15, quad = lane >> 4;

  // ---- staging geometry: issue i in {0,1} covers tile rows [i*64, i*64+64).
  // flat 16B chunk index = i*256 + tid  ->  row = chunk>>2, koff = (chunk&3)*8.
  const int srow  = tid >> 2;
  const int skoff = (tid & 3) * 8;
  int t0 = posTok[row0 + srow];      if (t0 < 0) t0 = 0;   // pad rows -> token 0 (never combined)
  int t1 = posTok[row0 + 64 + srow]; if (t1 < 0) t1 = 0;
  const unsigned short* gA0 = Xbf + (size_t)t0 * DH + skoff;
  const unsigned short* gA1 = Xbf + (size_t)t1 * DH + skoff;
  const unsigned short* gB0 = Wb + (size_t)(n0 + srow) * DH + skoff;
  const unsigned short* gB1 = Wb + (size_t)(n0 + 64 + srow) * DH + skoff;
  unsigned short* lA0 = As + (w * 64) * 8;          // wave-uniform LDS bases
  unsigned short* lA1 = As + (256 + w * 64) * 8;
  unsigned short* lB0 = Bs + (w * 64) * 8;
  unsigned short* lB1 = Bs + (256 + w * 64) * 8;

  const unsigned short* Ard = As + (size_t)(wm * 64 + l15) * 32 + quad * 8;
  const unsigned short* Brd = Bs + (size_t)(wn * 64 + l15) * 32 + quad * 8;

  f32x4 acc[4][4];
#pragma unroll
  for (int mi = 0; mi < 4; mi++)
#pragma unroll
    for (int ni = 0; ni < 4; ni++) acc[mi][ni] = (f32x4){0.f, 0.f, 0.f, 0.f};

  for (int k0 = 0; k0 < DH; k0 += 32) {
    gload_lds16(gA0, lA0);
    gload_lds16(gA1, lA1);
    gload_lds16(gB0, lB0);
    gload_lds16(gB1, lB1);
    gA0 += 32; gA1 += 32; gB0 += 32; gB1 += 32;
    __syncthreads();                 // drains vmcnt -> tile visible
    bf16x8 af[4], bv[4];
#pragma unroll
    for (int mi = 0; mi < 4; mi++) af[mi] = *(const bf16x8*)(Ard + mi * 16 * 32);
#pragma unroll
    for (int ni = 0; ni < 4; ni++) bv[ni] = *(const bf16x8*)(Brd + ni * 16 * 32);
#pragma unroll
    for (int mi = 0; mi < 4; mi++)
#pragma unroll
      for (int ni = 0; ni < 4; ni++)
        acc[mi][ni] = __builtin_amdgcn_mfma_f32_16x16x32_bf16(af[mi], bv[ni], acc[mi][ni], 0, 0, 0);
    __syncthreads();                 // reads done before next overwrite
  }

  const int rowb = row0 + wm * 64;
#pragma unroll
  for (int mi = 0; mi < 4; mi++) {
#pragma unroll
    for (int p = 0; p < 2; p++) {   // (ni=2p -> gate, ni=2p+1 -> up) same lane, same f
      f32x4 g = acc[mi][2 * p], u = acc[mi][2 * p + 1];
      int f = (n0 >> 1) + wn * 32 + p * 16 + l15;
#pragma unroll
      for (int r = 0; r < 4; r++) {
        int row = rowb + mi * 16 + quad * 4 + r;
        float gv = g[r];
        float hv = (gv / (1.f + __expf(-gv))) * u[r];
        H[(size_t)row * FF + f] = f2bf(hv);
      }
    }
  }
}

// ---------------- GEMM2 (m97 structure): Y = H @ Wdn'' ----------------
__global__ __launch_bounds__(256) void gemm2_kernel(
    const unsigned short* __restrict__ H,
    const unsigned short* __restrict__ Wdn,   // [NE][DH][FF] bf16 transposed
    const int* __restrict__ offs,
    unsigned short* __restrict__ Y)           // [PADROWS][DH] bf16
{
  __shared__ __align__(16) unsigned short As[128 * 32];
  __shared__ __align__(16) unsigned short Bs[128 * 32];
  const int n0 = blockIdx.x * 128;
  const int row0 = blockIdx.y * 128;
  if (row0 >= offs[NE]) return;
  int e = 0;
#pragma unroll
  for (int i = 1; i < NE; i++) e += (row0 >= offs[i]) ? 1 : 0;
  const unsigned short* Wb = Wdn + (size_t)e * DH * FF;

  const int tid = threadIdx.x;
  const int lane = tid & 63;
  const int w = tid >> 6;
  const int wm = w >> 1, wn = w & 1;
  const int l15 = lane & 15, quad = lane >> 4;

  const int srow  = tid >> 2;
  const int skoff = (tid & 3) * 8;
  const unsigned short* gA0 = H + (size_t)(row0 + srow) * FF + skoff;
  const unsigned short* gA1 = H + (size_t)(row0 + 64 + srow) * FF + skoff;
  const unsigned short* gB0 = Wb + (size_t)(n0 + srow) * FF + skoff;
  const unsigned short* gB1 = Wb + (size_t)(n0 + 64 + srow) * FF + skoff;
  unsigned short* lA0 = As + (w * 64) * 8;
  unsigned short* lA1 = As + (256 + w * 64) * 8;
  unsigned short* lB0 = Bs + (w * 64) * 8;
  unsigned short* lB1 = Bs + (256 + w * 64) * 8;

  const unsigned short* Ard = As + (size_t)(wm * 64 + l15) * 32 + quad * 8;
  const unsigned short* Brd = Bs + (size_t)(wn * 64 + l15) * 32 + quad * 8;

  f32x4 acc[4][4];
#pragma unroll
  for (int mi = 0; mi < 4; mi++)
#pragma unroll
    for (int ni = 0; ni < 4; ni++) acc[mi][ni] = (f32x4){0.f, 0.f, 0.f, 0.f};

  for (int k0 = 0; k0 < FF; k0 += 32) {
    gload_lds16(gA0, lA0);
    gload_lds16(gA1, lA1);
    gload_lds16(gB0, lB0);
    gload_lds16(gB1, lB1);
    gA0 += 32; gA1 += 32; gB0 += 32; gB1 += 32;
    __syncthreads();
    bf16x8 af[4], bv[4];
#pragma unroll
    for (int mi = 0; mi < 4; mi++) af[mi] = *(const bf16x8*)(Ard + mi * 16 * 32);
#pragma unroll
    for (int ni = 0; ni < 4; ni++) bv[ni] = *(const bf16x8*)(Brd + ni * 16 * 32);
#pragma unroll
    for (int mi = 0; mi < 4; mi++)
#pragma unroll
      for (int ni = 0; ni < 4; ni++)
        acc[mi][ni] = __builtin_amdgcn_mfma_f32_16x16x32_bf16(af[mi], bv[ni], acc[mi][ni], 0, 0, 0);
    __syncthreads();
  }

#pragma unroll
  for (int mi = 0; mi < 4; mi++)
#pragma unroll
    for (int ni = 0; ni < 4; ni++) {
      int col = n0 + wn * 64 + ni * 16 + l15;
#pragma unroll
      for (int r = 0; r < 4; r++) {
        int row = row0 + wm * 64 + mi * 16 + quad * 4 + r;
        Y[(size_t)row * DH + col] = f2bf(acc[mi][ni][r]);
      }
    }
}

// ---------------- combine: out[t] = w0*Y[p0] + w1*Y[p1]  (bf16 Y -> fp32 out) ----------------
__global__ void combine_kernel(const unsigned short* __restrict__ Y,
                               const int* __restrict__ posOf,
                               const float* __restrict__ tokW,
                               float* __restrict__ out)
{
  int idx = blockIdx.x * 256 + threadIdx.x;
  int t = idx >> 7;
  int c = (idx & 127) * 8;
  int p0 = posOf[2 * t], p1 = posOf[2 * t + 1];
  float w0 = tokW[2 * t], w1 = tokW[2 * t + 1];
  const uint4 a = *(const uint4*)&Y[(size_t)p0 * DH + c];
  const uint4 b = *(const uint4*)&Y[(size_t)p1 * DH + c];
  const unsigned* ap = (const unsigned*)&a;
  const unsigned* bp = (const unsigned*)&b;
  float4 o0, o1;
#pragma unroll
  for (int i = 0; i < 4; i++) {
    float a0 = bf2f((unsigned short)(ap[i] & 0xffff)), a1 = bf2f((unsigned short)(ap[i] >> 16));
    float b0 = bf2f((unsigned short)(bp[i] & 0xffff)), b1 = bf2f((unsigned short)(bp[i] >> 16));
    float r0 = w0 * a0 + w1 * b0;
    float r1 = w0 * a1 + w1 * b1;
    if (i < 2) { ((float*)&o0)[2 * i] = r0; ((float*)&o0)[2 * i + 1] = r1; }
    else       { ((float*)&o1)[2 * (i - 2)] = r0; ((float*)&o1)[2 * (i - 2) + 1] = r1; }
  }
  *(float4*)&out[(size_t)t * DH + c]     = o0;
  *(float4*)&out[(size_t)t * DH + c + 4] = o1;
}

extern "C" void kernel_launch(void* const* d_in, const int* in_sizes, int n_in,
                              void* d_out, int out_size, void* d_ws, size_t ws_size,
                              hipStream_t stream)
{
  const float* X   = (const float*)d_in[0];
  const float* GW  = (const float*)d_in[1];
  const float* GLD = (const float*)d_in[2];
  const float* GUP = (const float*)d_in[3];
  const float* DNP = (const float*)d_in[4];
  const float* GUA = (const float*)d_in[5];
  const float* GUB = (const float*)d_in[6];
  const float* DNA = (const float*)d_in[7];
  const float* DNB = (const float*)d_in[8];
  float* OUT = (float*)d_out;

  char* p = (char*)d_ws;
  unsigned short* Wguf = (unsigned short*)p; p += (size_t)NE * NC * DH * 2;   // 64 MiB
  unsigned short* Wdnf = (unsigned short*)p; p += (size_t)NE * DH * FF * 2;   // 32 MiB
  unsigned short* H    = (unsigned short*)p; p += (size_t)PADROWS * FF * 2;   // 132 MiB
  unsigned short* Y    = (unsigned short*)p; p += (size_t)PADROWS * DH * 2;   // 66 MiB
  int*   posTok = (int*)p;   p += (size_t)PADROWS * 4;
  int*   posOf  = (int*)p;   p += (size_t)T_TOK * 2 * 4;
  int*   tokE   = (int*)p;   p += (size_t)T_TOK * 2 * 4;
  float* tokW   = (float*)p; p += (size_t)T_TOK * 2 * 4;
  int*   counts = (int*)p;   p += 32;
  int*   cursor = (int*)p;   p += 32;
  int*   offs   = (int*)p;   p += 64;
  if ((size_t)(p - (char*)d_ws) > ws_size) return;  // workspace too small

  // Xbf (32 MiB) aliases Y (66 MiB): Xbf is only read by gemm1; Y is only
  // written by gemm2 (after gemm1) and read by combine. Same-stream serial.
  unsigned short* Xbf = Y;

  hipMemsetAsync(counts, 0, 32 + 32 + 64, stream);   // counts+cursor+offs
  hipMemsetAsync(posTok, 0xFF, (size_t)PADROWS * 4, stream);

  fold_gu_kernel<<<dim3(NE, DH / 64, NC / 64), 256, 0, stream>>>(GUP, GUA, GUB, Wguf);
  fold_dn_kernel<<<dim3(NE, FF / 64, DH / 64), 256, 0, stream>>>(DNP, DNA, DNB, Wdnf);
  cvtx_kernel<<<(T_TOK * DH / 8) / 256, 256, 0, stream>>>(X, Xbf);
  route_kernel<<<T_TOK / 32, 256, 0, stream>>>(X, GW, GLD, tokE, tokW, counts);
  offs_kernel<<<1, 64, 0, stream>>>(counts, offs);
  scatter_kernel<<<T_TOK / 256, 256, 0, stream>>>(tokE, offs, cursor, posTok, posOf);
  gemm1_kernel<<<dim3(NC / 128, PADROWS / 128), 256, 0, stream>>>(Xbf, Wguf, posTok, offs, H);
  gemm2_kernel<<<dim3(DH / 128, PADROWS / 128), 256, 0, stream>>>(H, Wdnf, offs, Y);
  combine_kernel<<<(T_TOK * DH / 8) / 256, 256, 0, stream>>>(Y, posOf, tokW, OUT);
}

// Round 2
// 943.921 us; speedup vs baseline: 2.5433x; 1.0494x over previous
//
#include <hip/hip_runtime.h>
#include <stdint.h>

// Problem constants
#define T_TOK 16384
#define DH    1024
#define FF    2048
#define NE    8
#define NC    4096          // 2F
#define PADROWS 33792       // 264 * 128  (T*K rounded up with per-expert 128-padding)

typedef __attribute__((ext_vector_type(8))) __bf16 bf16x8;
typedef __attribute__((ext_vector_type(4))) float  f32x4;

__device__ __forceinline__ float bf2f(unsigned short s) {
  unsigned int u = ((unsigned int)s) << 16;
  return __builtin_bit_cast(float, u);
}
__device__ __forceinline__ unsigned short f2bf(float f) {
  unsigned int u = __builtin_bit_cast(unsigned int, f);
  u += 0x7fffu + ((u >> 16) & 1u);          // RNE
  return (unsigned short)(u >> 16);
}

// async global->LDS, 16B per lane. Global src is PER-LANE; LDS dest is
// wave-uniform base + lane*16 (hardware-defined linear scatter).
__device__ __forceinline__ void gload_lds16(const void* g, void* l) {
  __builtin_amdgcn_global_load_lds(
      (__attribute__((address_space(1))) void*)(uintptr_t)g,
      (__attribute__((address_space(3))) void*)(uint32_t)(uintptr_t)l,
      16, 0, 0);
}

// interleaved column mapping: c'' in [0,4096) -> original gate_up column.
// group g = c''>>5; within: [0,16) -> gate f=g*16+wi, [16,32) -> up (orig 2048+f)
__device__ __forceinline__ int origc_gu(int c) {
  int g = c >> 5, wi = c & 31;
  return ((wi >> 4) << 11) | (g * 16 + (wi & 15));
}

// ---------------- fold kernels: W' = W + 2*A^T B^T, fp32 in -> bf16 out, TRANSPOSED [N][K] ----------------
// Vectorized rewrite: float4 global reads, LDS-tile transpose, uint4 (8x bf16) stores.
__global__ __launch_bounds__(256) void fold_gu_kernel(
    const float* __restrict__ Wg,   // [NE][DH][NC] fp32
    const float* __restrict__ A,    // [NE][16][DH] fp32
    const float* __restrict__ B,    // [NE][NC][16] fp32
    unsigned short* __restrict__ Wf) // [NE][NC][DH] bf16, interleaved cols
{
  const int e = blockIdx.x, d0 = blockIdx.y * 64, c0 = blockIdx.z * 64;
  __shared__ float tile[64][65];   // [d][c]
  __shared__ float Al[16][64];     // [r][d]
  __shared__ float Bl[64][17];     // [c][r]
  const int tid = threadIdx.x;
  {
    int r = tid >> 4, dc = (tid & 15) * 4;
    float4 v = *(const float4*)&A[((size_t)e * 16 + r) * DH + d0 + dc];
    Al[r][dc] = v.x; Al[r][dc + 1] = v.y; Al[r][dc + 2] = v.z; Al[r][dc + 3] = v.w;
  }
  {
    int c = tid >> 2, rr = (tid & 3) * 4;
    float4 v = *(const float4*)&B[((size_t)e * NC + origc_gu(c0 + c)) * 16 + rr];
    Bl[c][rr] = v.x; Bl[c][rr + 1] = v.y; Bl[c][rr + 2] = v.z; Bl[c][rr + 3] = v.w;
  }
  __syncthreads();
  const int d = tid >> 2;            // 0..63
  const int cq0 = (tid & 3) * 4;     // 0,4,8,12
  float areg[16];
#pragma unroll
  for (int r = 0; r < 16; r++) areg[r] = Al[r][d];
#pragma unroll
  for (int p = 0; p < 4; p++) {
    const int cq = p * 16 + cq0;     // 4-span stays inside one 16-col half-group
    float4 v = *(const float4*)&Wg[((size_t)e * DH + d0 + d) * NC + origc_gu(c0 + cq)];
    float s0 = 0.f, s1 = 0.f, s2 = 0.f, s3 = 0.f;
#pragma unroll
    for (int r = 0; r < 16; r++) {
      float a = areg[r];
      s0 += a * Bl[cq][r];     s1 += a * Bl[cq + 1][r];
      s2 += a * Bl[cq + 2][r]; s3 += a * Bl[cq + 3][r];
    }
    tile[d][cq]     = v.x + 2.f * s0; tile[d][cq + 1] = v.y + 2.f * s1;
    tile[d][cq + 2] = v.z + 2.f * s2; tile[d][cq + 3] = v.w + 2.f * s3;
  }
  __syncthreads();
#pragma unroll
  for (int p = 0; p < 2; p++) {
    int flat = p * 256 + tid;
    int c = flat >> 3, dch = (flat & 7) * 8;
    unsigned short u[8];
#pragma unroll
    for (int j = 0; j < 8; j++) u[j] = f2bf(tile[dch + j][c]);
    *(uint4*)&Wf[((size_t)e * NC + c0 + c) * DH + d0 + dch] = *(uint4*)u;
  }
}

__global__ __launch_bounds__(256) void fold_dn_kernel(
    const float* __restrict__ Wd,   // [NE][FF][DH] fp32
    const float* __restrict__ A,    // [NE][16][FF] fp32
    const float* __restrict__ B,    // [NE][DH][16] fp32
    unsigned short* __restrict__ Wf) // [NE][DH][FF] bf16
{
  const int e = blockIdx.x, f0 = blockIdx.y * 64, d0 = blockIdx.z * 64;
  __shared__ float tile[64][65];   // [f][d]
  __shared__ float Al[16][64];     // [r][f]
  __shared__ float Bl[64][17];     // [d][r]
  const int tid = threadIdx.x;
  {
    int r = tid >> 4, fc = (tid & 15) * 4;
    float4 v = *(const float4*)&A[((size_t)e * 16 + r) * FF + f0 + fc];
    Al[r][fc] = v.x; Al[r][fc + 1] = v.y; Al[r][fc + 2] = v.z; Al[r][fc + 3] = v.w;
  }
  {
    int d = tid >> 2, rr = (tid & 3) * 4;
    float4 v = *(const float4*)&B[((size_t)e * DH + d0 + d) * 16 + rr];
    Bl[d][rr] = v.x; Bl[d][rr + 1] = v.y; Bl[d][rr + 2] = v.z; Bl[d][rr + 3] = v.w;
  }
  __syncthreads();
  const int f = tid >> 2;            // 0..63
  const int dq0 = (tid & 3) * 4;     // 0,4,8,12
  float areg[16];
#pragma unroll
  for (int r = 0; r < 16; r++) areg[r] = Al[r][f];
#pragma unroll
  for (int p = 0; p < 4; p++) {
    const int dq = p * 16 + dq0;
    float4 v = *(const float4*)&Wd[((size_t)e * FF + f0 + f) * DH + d0 + dq];
    float s0 = 0.f, s1 = 0.f, s2 = 0.f, s3 = 0.f;
#pragma unroll
    for (int r = 0; r < 16; r++) {
      float a = areg[r];
      s0 += a * Bl[dq][r];     s1 += a * Bl[dq + 1][r];
      s2 += a * Bl[dq + 2][r]; s3 += a * Bl[dq + 3][r];
    }
    tile[f][dq]     = v.x + 2.f * s0; tile[f][dq + 1] = v.y + 2.f * s1;
    tile[f][dq + 2] = v.z + 2.f * s2; tile[f][dq + 3] = v.w + 2.f * s3;
  }
  __syncthreads();
#pragma unroll
  for (int p = 0; p < 2; p++) {
    int flat = p * 256 + tid;
    int d = flat >> 3, fch = (flat & 7) * 8;
    unsigned short u[8];
#pragma unroll
    for (int j = 0; j < 8; j++) u[j] = f2bf(tile[fch + j][d]);
    *(uint4*)&Wf[((size_t)e * DH + d0 + d) * FF + f0 + fch] = *(uint4*)u;
  }
}

// ---------------- routing: logits -> top-2 -> weights; also emits Xbf (fp32->bf16) ----------------
__global__ __launch_bounds__(256) void route_kernel(
    const float* __restrict__ X,
    const float* __restrict__ GW,
    const float* __restrict__ GLD,
    unsigned short* __restrict__ Xbf,
    int* __restrict__ tokE, float* __restrict__ tokW, int* __restrict__ counts)
{
  __shared__ float gc[NE * DH];
  __shared__ int bc[NE];
  const int tid = threadIdx.x;
  if (tid < NE) bc[tid] = 0;
  for (int i = tid; i < NE * DH; i += 256) gc[i] = GW[i] + GLD[i];
  __syncthreads();
  const int w = tid >> 6, lane = tid & 63;
  for (int it = 0; it < 8; it++) {
    const int t = blockIdx.x * 32 + w * 8 + it;
    float s[NE];
#pragma unroll
    for (int e = 0; e < NE; e++) s[e] = 0.f;
#pragma unroll
    for (int i = 0; i < 8; i++) {
      const int base = 2 * lane + 128 * i;
      const float2 xv = *(const float2*)&X[(size_t)t * DH + base];
      // fused X -> bf16 conversion (replaces the separate cvtx pass)
      *(unsigned*)&Xbf[(size_t)t * DH + base] =
          (unsigned)f2bf(xv.x) | ((unsigned)f2bf(xv.y) << 16);
#pragma unroll
      for (int e = 0; e < NE; e++) {
        float2 g2 = *(const float2*)&gc[e * DH + base];
        s[e] += xv.x * g2.x + xv.y * g2.y;
      }
    }
#pragma unroll
    for (int e = 0; e < NE; e++) {
#pragma unroll
      for (int off = 32; off > 0; off >>= 1) s[e] += __shfl_xor(s[e], off);
    }
    int e1 = 0; float l1 = s[0];
#pragma unroll
    for (int e = 1; e < NE; e++) { if (s[e] > l1) { l1 = s[e]; e1 = e; } }
    int e2i = 0; float l2 = -3.4e38f;
#pragma unroll
    for (int e = 0; e < NE; e++) { if (e != e1 && s[e] > l2) { l2 = s[e]; e2i = e; } }
    float r = __expf(l2 - l1);
    float w0 = 1.f / (1.f + r);
    if (lane == 0) {
      tokE[2 * t] = e1; tokE[2 * t + 1] = e2i;
      tokW[2 * t] = w0; tokW[2 * t + 1] = 1.f - w0;
      atomicAdd(&bc[e1], 1); atomicAdd(&bc[e2i], 1);
    }
  }
  __syncthreads();
  if (tid < NE) atomicAdd(&counts[tid], bc[tid]);
}

__global__ void offs_kernel(const int* __restrict__ counts, int* __restrict__ offs) {
  if (threadIdx.x == 0) {
    int run = 0;
#pragma unroll
    for (int e = 0; e < NE; e++) { offs[e] = run; run += (counts[e] + 127) & ~127; }
    offs[NE] = run;
  }
}

__global__ void scatter_kernel(const int* __restrict__ tokE,
                               const int* __restrict__ offs,
                               int* __restrict__ cursor,
                               int* __restrict__ posTok,
                               int* __restrict__ posOf)
{
  const int t = blockIdx.x * 256 + threadIdx.x;
  const int lane = threadIdx.x & 63;
#pragma unroll
  for (int k = 0; k < 2; k++) {
    const int e = tokE[2 * t + k];
    int p = 0;
#pragma unroll
    for (int ei = 0; ei < NE; ei++) {
      unsigned long long mask = __ballot(e == ei);
      if (mask) {
        int leader = __ffsll((unsigned long long)mask) - 1;
        int base = 0;
        if (lane == leader) base = atomicAdd(&cursor[ei], (int)__popcll(mask));
        base = __shfl(base, leader);
        if (e == ei)
          p = offs[ei] + base + (int)__popcll(mask & ((1ull << lane) - 1ull));
      }
    }
    if (p < 0) p = 0;
    if (p >= PADROWS) p = PADROWS - 1;
    posTok[p] = t;
    posOf[2 * t + k] = p;
  }
}

// ---------------- GEMM1 (m97 structure): H = silu/up( gather(Xbf) @ Wgu'' ) ----------------
// 128x128 tile, BK=32, 16KiB LDS, global_load_lds width-16 staging, 2 barriers/K-step.
__global__ __launch_bounds__(256) void gemm1_kernel(
    const unsigned short* __restrict__ Xbf,   // [T][DH] bf16
    const unsigned short* __restrict__ Wgu,   // [NE][NC][DH] bf16 transposed+interleaved
    const int* __restrict__ posTok,
    const int* __restrict__ offs,
    unsigned short* __restrict__ H)           // [PADROWS][FF] bf16
{
  __shared__ __align__(16) unsigned short As[128 * 32];   // [row][k] 8 KiB
  __shared__ __align__(16) unsigned short Bs[128 * 32];   // [col][k] 8 KiB
  const int n0 = blockIdx.x * 128;
  const int row0 = blockIdx.y * 128;
  if (row0 >= offs[NE]) return;
  int e = 0;
#pragma unroll
  for (int i = 1; i < NE; i++) e += (row0 >= offs[i]) ? 1 : 0;
  const unsigned short* Wb = Wgu + (size_t)e * NC * DH;

  const int tid = threadIdx.x;
  const int lane = tid & 63;
  const int w = tid >> 6;
  const int wm = w >> 1, wn = w & 1;
  const int l15 = lane & 15, quad = lane >> 4;

  const int srow  = tid >> 2;
  const int skoff = (tid & 3) * 8;
  int t0 = posTok[row0 + srow];      if (t0 < 0) t0 = 0;   // pad rows -> token 0 (never combined)
  int t1 = posTok[row0 + 64 + srow]; if (t1 < 0) t1 = 0;
  const unsigned short* gA0 = Xbf + (size_t)t0 * DH + skoff;
  const unsigned short* gA1 = Xbf + (size_t)t1 * DH + skoff;
  const unsigned short* gB0 = Wb + (size_t)(n0 + srow) * DH + skoff;
  const unsigned short* gB1 = Wb + (size_t)(n0 + 64 + srow) * DH + skoff;
  unsigned short* lA0 = As + (w * 64) * 8;          // wave-uniform LDS bases
  unsigned short* lA1 = As + (256 + w * 64) * 8;
  unsigned short* lB0 = Bs + (w * 64) * 8;
  unsigned short* lB1 = Bs + (256 + w * 64) * 8;

  const unsigned short* Ard = As + (size_t)(wm * 64 + l15) * 32 + quad * 8;
  const unsigned short* Brd = Bs + (size_t)(wn * 64 + l15) * 32 + quad * 8;

  f32x4 acc[4][4];
#pragma unroll
  for (int mi = 0; mi < 4; mi++)
#pragma unroll
    for (int ni = 0; ni < 4; ni++) acc[mi][ni] = (f32x4){0.f, 0.f, 0.f, 0.f};

  for (int k0 = 0; k0 < DH; k0 += 32) {
    gload_lds16(gA0, lA0);
    gload_lds16(gA1, lA1);
    gload_lds16(gB0, lB0);
    gload_lds16(gB1, lB1);
    gA0 += 32; gA1 += 32; gB0 += 32; gB1 += 32;
    __syncthreads();                 // drains vmcnt -> tile visible
    bf16x8 af[4], bv[4];
#pragma unroll
    for (int mi = 0; mi < 4; mi++) af[mi] = *(const bf16x8*)(Ard + mi * 16 * 32);
#pragma unroll
    for (int ni = 0; ni < 4; ni++) bv[ni] = *(const bf16x8*)(Brd + ni * 16 * 32);
#pragma unroll
    for (int mi = 0; mi < 4; mi++)
#pragma unroll
      for (int ni = 0; ni < 4; ni++)
        acc[mi][ni] = __builtin_amdgcn_mfma_f32_16x16x32_bf16(af[mi], bv[ni], acc[mi][ni], 0, 0, 0);
    __syncthreads();                 // reads done before next overwrite
  }

  const int rowb = row0 + wm * 64;
#pragma unroll
  for (int mi = 0; mi < 4; mi++) {
#pragma unroll
    for (int p = 0; p < 2; p++) {   // (ni=2p -> gate, ni=2p+1 -> up) same lane, same f
      f32x4 g = acc[mi][2 * p], u = acc[mi][2 * p + 1];
      int f = (n0 >> 1) + wn * 32 + p * 16 + l15;
#pragma unroll
      for (int r = 0; r < 4; r++) {
        int row = rowb + mi * 16 + quad * 4 + r;
        float gv = g[r];
        float hv = (gv / (1.f + __expf(-gv))) * u[r];
        H[(size_t)row * FF + f] = f2bf(hv);
      }
    }
  }
}

// ---------------- GEMM2 (m97 structure): Y = H @ Wdn'' ----------------
__global__ __launch_bounds__(256) void gemm2_kernel(
    const unsigned short* __restrict__ H,
    const unsigned short* __restrict__ Wdn,   // [NE][DH][FF] bf16 transposed
    const int* __restrict__ offs,
    unsigned short* __restrict__ Y)           // [PADROWS][DH] bf16
{
  __shared__ __align__(16) unsigned short As[128 * 32];
  __shared__ __align__(16) unsigned short Bs[128 * 32];
  const int n0 = blockIdx.x * 128;
  const int row0 = blockIdx.y * 128;
  if (row0 >= offs[NE]) return;
  int e = 0;
#pragma unroll
  for (int i = 1; i < NE; i++) e += (row0 >= offs[i]) ? 1 : 0;
  const unsigned short* Wb = Wdn + (size_t)e * DH * FF;

  const int tid = threadIdx.x;
  const int lane = tid & 63;
  const int w = tid >> 6;
  const int wm = w >> 1, wn = w & 1;
  const int l15 = lane & 15, quad = lane >> 4;

  const int srow  = tid >> 2;
  const int skoff = (tid & 3) * 8;
  const unsigned short* gA0 = H + (size_t)(row0 + srow) * FF + skoff;
  const unsigned short* gA1 = H + (size_t)(row0 + 64 + srow) * FF + skoff;
  const unsigned short* gB0 = Wb + (size_t)(n0 + srow) * FF + skoff;
  const unsigned short* gB1 = Wb + (size_t)(n0 + 64 + srow) * FF + skoff;
  unsigned short* lA0 = As + (w * 64) * 8;
  unsigned short* lA1 = As + (256 + w * 64) * 8;
  unsigned short* lB0 = Bs + (w * 64) * 8;
  unsigned short* lB1 = Bs + (256 + w * 64) * 8;

  const unsigned short* Ard = As + (size_t)(wm * 64 + l15) * 32 + quad * 8;
  const unsigned short* Brd = Bs + (size_t)(wn * 64 + l15) * 32 + quad * 8;

  f32x4 acc[4][4];
#pragma unroll
  for (int mi = 0; mi < 4; mi++)
#pragma unroll
    for (int ni = 0; ni < 4; ni++) acc[mi][ni] = (f32x4){0.f, 0.f, 0.f, 0.f};

  for (int k0 = 0; k0 < FF; k0 += 32) {
    gload_lds16(gA0, lA0);
    gload_lds16(gA1, lA1);
    gload_lds16(gB0, lB0);
    gload_lds16(gB1, lB1);
    gA0 += 32; gA1 += 32; gB0 += 32; gB1 += 32;
    __syncthreads();
    bf16x8 af[4], bv[4];
#pragma unroll
    for (int mi = 0; mi < 4; mi++) af[mi] = *(const bf16x8*)(Ard + mi * 16 * 32);
#pragma unroll
    for (int ni = 0; ni < 4; ni++) bv[ni] = *(const bf16x8*)(Brd + ni * 16 * 32);
#pragma unroll
    for (int mi = 0; mi < 4; mi++)
#pragma unroll
      for (int ni = 0; ni < 4; ni++)
        acc[mi][ni] = __builtin_amdgcn_mfma_f32_16x16x32_bf16(af[mi], bv[ni], acc[mi][ni], 0, 0, 0);
    __syncthreads();
  }

#pragma unroll
  for (int mi = 0; mi < 4; mi++)
#pragma unroll
    for (int ni = 0; ni < 4; ni++) {
      int col = n0 + wn * 64 + ni * 16 + l15;
#pragma unroll
      for (int r = 0; r < 4; r++) {
        int row = row0 + wm * 64 + mi * 16 + quad * 4 + r;
        Y[(size_t)row * DH + col] = f2bf(acc[mi][ni][r]);
      }
    }
}

// ---------------- combine: out[t] = w0*Y[p0] + w1*Y[p1]  (bf16 Y -> fp32 out) ----------------
__global__ void combine_kernel(const unsigned short* __restrict__ Y,
                               const int* __restrict__ posOf,
                               const float* __restrict__ tokW,
                               float* __restrict__ out)
{
  int idx = blockIdx.x * 256 + threadIdx.x;
  int t = idx >> 7;
  int c = (idx & 127) * 8;
  int p0 = posOf[2 * t], p1 = posOf[2 * t + 1];
  float w0 = tokW[2 * t], w1 = tokW[2 * t + 1];
  const uint4 a = *(const uint4*)&Y[(size_t)p0 * DH + c];
  const uint4 b = *(const uint4*)&Y[(size_t)p1 * DH + c];
  const unsigned* ap = (const unsigned*)&a;
  const unsigned* bp = (const unsigned*)&b;
  float4 o0, o1;
#pragma unroll
  for (int i = 0; i < 4; i++) {
    float a0 = bf2f((unsigned short)(ap[i] & 0xffff)), a1 = bf2f((unsigned short)(ap[i] >> 16));
    float b0 = bf2f((unsigned short)(bp[i] & 0xffff)), b1 = bf2f((unsigned short)(bp[i] >> 16));
    float r0 = w0 * a0 + w1 * b0;
    float r1 = w0 * a1 + w1 * b1;
    if (i < 2) { ((float*)&o0)[2 * i] = r0; ((float*)&o0)[2 * i + 1] = r1; }
    else       { ((float*)&o1)[2 * (i - 2)] = r0; ((float*)&o1)[2 * (i - 2) + 1] = r1; }
  }
  *(float4*)&out[(size_t)t * DH + c]     = o0;
  *(float4*)&out[(size_t)t * DH + c + 4] = o1;
}

extern "C" void kernel_launch(void* const* d_in, const int* in_sizes, int n_in,
                              void* d_out, int out_size, void* d_ws, size_t ws_size,
                              hipStream_t stream)
{
  const float* X   = (const float*)d_in[0];
  const float* GW  = (const float*)d_in[1];
  const float* GLD = (const float*)d_in[2];
  const float* GUP = (const float*)d_in[3];
  const float* DNP = (const float*)d_in[4];
  const float* GUA = (const float*)d_in[5];
  const float* GUB = (const float*)d_in[6];
  const float* DNA = (const float*)d_in[7];
  const float* DNB = (const float*)d_in[8];
  float* OUT = (float*)d_out;

  char* p = (char*)d_ws;
  unsigned short* Wguf = (unsigned short*)p; p += (size_t)NE * NC * DH * 2;   // 64 MiB
  unsigned short* Wdnf = (unsigned short*)p; p += (size_t)NE * DH * FF * 2;   // 32 MiB
  unsigned short* H    = (unsigned short*)p; p += (size_t)PADROWS * FF * 2;   // 132 MiB
  unsigned short* Y    = (unsigned short*)p; p += (size_t)PADROWS * DH * 2;   // 66 MiB
  int*   posTok = (int*)p;   p += (size_t)PADROWS * 4;
  int*   posOf  = (int*)p;   p += (size_t)T_TOK * 2 * 4;
  int*   tokE   = (int*)p;   p += (size_t)T_TOK * 2 * 4;
  float* tokW   = (float*)p; p += (size_t)T_TOK * 2 * 4;
  int*   counts = (int*)p;   p += 32;
  int*   cursor = (int*)p;   p += 32;
  int*   offs   = (int*)p;   p += 64;
  if ((size_t)(p - (char*)d_ws) > ws_size) return;  // workspace too small

  // Xbf (32 MiB) aliases Y (66 MiB): Xbf is written by route, read by gemm1;
  // Y is only written by gemm2 (after gemm1) and read by combine. Same-stream serial.
  unsigned short* Xbf = Y;

  hipMemsetAsync(counts, 0, 32 + 32 + 64, stream);   // counts+cursor+offs
  hipMemsetAsync(posTok, 0xFF, (size_t)PADROWS * 4, stream);

  fold_gu_kernel<<<dim3(NE, DH / 64, NC / 64), 256, 0, stream>>>(GUP, GUA, GUB, Wguf);
  fold_dn_kernel<<<dim3(NE, FF / 64, DH / 64), 256, 0, stream>>>(DNP, DNA, DNB, Wdnf);
  route_kernel<<<T_TOK / 32, 256, 0, stream>>>(X, GW, GLD, Xbf, tokE, tokW, counts);
  offs_kernel<<<1, 64, 0, stream>>>(counts, offs);
  scatter_kernel<<<T_TOK / 256, 256, 0, stream>>>(tokE, offs, cursor, posTok, posOf);
  gemm1_kernel<<<dim3(NC / 128, PADROWS / 128), 256, 0, stream>>>(Xbf, Wguf, posTok, offs, H);
  gemm2_kernel<<<dim3(DH / 128, PADROWS / 128), 256, 0, stream>>>(H, Wdnf, offs, Y);
  combine_kernel<<<(T_TOK * DH / 8) / 256, 256, 0, stream>>>(Y, posOf, tokW, OUT);
}

// Round 3
// 925.430 us; speedup vs baseline: 2.5941x; 1.0200x over previous
//
#include <hip/hip_runtime.h>
#include <stdint.h>

// Problem constants
#define T_TOK 16384
#define DH    1024
#define FF    2048
#define NE    8
#define NC    4096          // 2F
#define PADROWS 34816       // 136 * 256  (T*K rounded up with per-expert 256-padding)
#define BK    32

typedef __attribute__((ext_vector_type(8))) __bf16 bf16x8;
typedef __attribute__((ext_vector_type(4))) float  f32x4;

__device__ __forceinline__ float bf2f(unsigned short s) {
  unsigned int u = ((unsigned int)s) << 16;
  return __builtin_bit_cast(float, u);
}
__device__ __forceinline__ unsigned short f2bf(float f) {
  unsigned int u = __builtin_bit_cast(unsigned int, f);
  u += 0x7fffu + ((u >> 16) & 1u);          // RNE
  return (unsigned short)(u >> 16);
}

// async global->LDS, 16B per lane. Global src is PER-LANE; LDS dest is
// wave-uniform base + lane*16 (hardware-defined linear scatter).
__device__ __forceinline__ void gload_lds16(const void* g, void* l) {
  __builtin_amdgcn_global_load_lds(
      (__attribute__((address_space(1))) void*)(uintptr_t)g,
      (__attribute__((address_space(3))) void*)(uint32_t)(uintptr_t)l,
      16, 0, 0);
}

// interleaved column mapping: c'' in [0,4096) -> original gate_up column.
__device__ __forceinline__ int origc_gu(int c) {
  int g = c >> 5, wi = c & 31;
  return ((wi >> 4) << 11) | (g * 16 + (wi & 15));
}

// ---------------- fold kernels (unchanged from R2): W' = W + 2*A^T B^T, fp32 -> bf16 transposed ----------------
__global__ __launch_bounds__(256) void fold_gu_kernel(
    const float* __restrict__ Wg, const float* __restrict__ A,
    const float* __restrict__ B, unsigned short* __restrict__ Wf)
{
  const int e = blockIdx.x, d0 = blockIdx.y * 64, c0 = blockIdx.z * 64;
  __shared__ float tile[64][65];
  __shared__ float Al[16][64];
  __shared__ float Bl[64][17];
  const int tid = threadIdx.x;
  {
    int r = tid >> 4, dc = (tid & 15) * 4;
    float4 v = *(const float4*)&A[((size_t)e * 16 + r) * DH + d0 + dc];
    Al[r][dc] = v.x; Al[r][dc + 1] = v.y; Al[r][dc + 2] = v.z; Al[r][dc + 3] = v.w;
  }
  {
    int c = tid >> 2, rr = (tid & 3) * 4;
    float4 v = *(const float4*)&B[((size_t)e * NC + origc_gu(c0 + c)) * 16 + rr];
    Bl[c][rr] = v.x; Bl[c][rr + 1] = v.y; Bl[c][rr + 2] = v.z; Bl[c][rr + 3] = v.w;
  }
  __syncthreads();
  const int d = tid >> 2;
  const int cq0 = (tid & 3) * 4;
  float areg[16];
#pragma unroll
  for (int r = 0; r < 16; r++) areg[r] = Al[r][d];
#pragma unroll
  for (int p = 0; p < 4; p++) {
    const int cq = p * 16 + cq0;
    float4 v = *(const float4*)&Wg[((size_t)e * DH + d0 + d) * NC + origc_gu(c0 + cq)];
    float s0 = 0.f, s1 = 0.f, s2 = 0.f, s3 = 0.f;
#pragma unroll
    for (int r = 0; r < 16; r++) {
      float a = areg[r];
      s0 += a * Bl[cq][r];     s1 += a * Bl[cq + 1][r];
      s2 += a * Bl[cq + 2][r]; s3 += a * Bl[cq + 3][r];
    }
    tile[d][cq]     = v.x + 2.f * s0; tile[d][cq + 1] = v.y + 2.f * s1;
    tile[d][cq + 2] = v.z + 2.f * s2; tile[d][cq + 3] = v.w + 2.f * s3;
  }
  __syncthreads();
#pragma unroll
  for (int p = 0; p < 2; p++) {
    int flat = p * 256 + tid;
    int c = flat >> 3, dch = (flat & 7) * 8;
    unsigned short u[8];
#pragma unroll
    for (int j = 0; j < 8; j++) u[j] = f2bf(tile[dch + j][c]);
    *(uint4*)&Wf[((size_t)e * NC + c0 + c) * DH + d0 + dch] = *(uint4*)u;
  }
}

__global__ __launch_bounds__(256) void fold_dn_kernel(
    const float* __restrict__ Wd, const float* __restrict__ A,
    const float* __restrict__ B, unsigned short* __restrict__ Wf)
{
  const int e = blockIdx.x, f0 = blockIdx.y * 64, d0 = blockIdx.z * 64;
  __shared__ float tile[64][65];
  __shared__ float Al[16][64];
  __shared__ float Bl[64][17];
  const int tid = threadIdx.x;
  {
    int r = tid >> 4, fc = (tid & 15) * 4;
    float4 v = *(const float4*)&A[((size_t)e * 16 + r) * FF + f0 + fc];
    Al[r][fc] = v.x; Al[r][fc + 1] = v.y; Al[r][fc + 2] = v.z; Al[r][fc + 3] = v.w;
  }
  {
    int d = tid >> 2, rr = (tid & 3) * 4;
    float4 v = *(const float4*)&B[((size_t)e * DH + d0 + d) * 16 + rr];
    Bl[d][rr] = v.x; Bl[d][rr + 1] = v.y; Bl[d][rr + 2] = v.z; Bl[d][rr + 3] = v.w;
  }
  __syncthreads();
  const int f = tid >> 2;
  const int dq0 = (tid & 3) * 4;
  float areg[16];
#pragma unroll
  for (int r = 0; r < 16; r++) areg[r] = Al[r][f];
#pragma unroll
  for (int p = 0; p < 4; p++) {
    const int dq = p * 16 + dq0;
    float4 v = *(const float4*)&Wd[((size_t)e * FF + f0 + f) * DH + d0 + dq];
    float s0 = 0.f, s1 = 0.f, s2 = 0.f, s3 = 0.f;
#pragma unroll
    for (int r = 0; r < 16; r++) {
      float a = areg[r];
      s0 += a * Bl[dq][r];     s1 += a * Bl[dq + 1][r];
      s2 += a * Bl[dq + 2][r]; s3 += a * Bl[dq + 3][r];
    }
    tile[f][dq]     = v.x + 2.f * s0; tile[f][dq + 1] = v.y + 2.f * s1;
    tile[f][dq + 2] = v.z + 2.f * s2; tile[f][dq + 3] = v.w + 2.f * s3;
  }
  __syncthreads();
#pragma unroll
  for (int p = 0; p < 2; p++) {
    int flat = p * 256 + tid;
    int d = flat >> 3, fch = (flat & 7) * 8;
    unsigned short u[8];
#pragma unroll
    for (int j = 0; j < 8; j++) u[j] = f2bf(tile[fch + j][d]);
    *(uint4*)&Wf[((size_t)e * DH + d0 + d) * FF + f0 + fch] = *(uint4*)u;
  }
}

// ---------------- routing: logits -> top-2 -> weights; also emits Xbf ----------------
__global__ __launch_bounds__(256) void route_kernel(
    const float* __restrict__ X,
    const float* __restrict__ GW,
    const float* __restrict__ GLD,
    unsigned short* __restrict__ Xbf,
    int* __restrict__ tokE, float* __restrict__ tokW, int* __restrict__ counts)
{
  __shared__ float gc[NE * DH];
  __shared__ int bc[NE];
  const int tid = threadIdx.x;
  if (tid < NE) bc[tid] = 0;
  for (int i = tid; i < NE * DH; i += 256) gc[i] = GW[i] + GLD[i];
  __syncthreads();
  const int w = tid >> 6, lane = tid & 63;
  for (int it = 0; it < 8; it++) {
    const int t = blockIdx.x * 32 + w * 8 + it;
    float s[NE];
#pragma unroll
    for (int e = 0; e < NE; e++) s[e] = 0.f;
#pragma unroll
    for (int i = 0; i < 8; i++) {
      const int base = 2 * lane + 128 * i;
      const float2 xv = *(const float2*)&X[(size_t)t * DH + base];
      *(unsigned*)&Xbf[(size_t)t * DH + base] =
          (unsigned)f2bf(xv.x) | ((unsigned)f2bf(xv.y) << 16);
#pragma unroll
      for (int e = 0; e < NE; e++) {
        float2 g2 = *(const float2*)&gc[e * DH + base];
        s[e] += xv.x * g2.x + xv.y * g2.y;
      }
    }
#pragma unroll
    for (int e = 0; e < NE; e++) {
#pragma unroll
      for (int off = 32; off > 0; off >>= 1) s[e] += __shfl_xor(s[e], off);
    }
    int e1 = 0; float l1 = s[0];
#pragma unroll
    for (int e = 1; e < NE; e++) { if (s[e] > l1) { l1 = s[e]; e1 = e; } }
    int e2i = 0; float l2 = -3.4e38f;
#pragma unroll
    for (int e = 0; e < NE; e++) { if (e != e1 && s[e] > l2) { l2 = s[e]; e2i = e; } }
    float r = __expf(l2 - l1);
    float w0 = 1.f / (1.f + r);
    if (lane == 0) {
      tokE[2 * t] = e1; tokE[2 * t + 1] = e2i;
      tokW[2 * t] = w0; tokW[2 * t + 1] = 1.f - w0;
      atomicAdd(&bc[e1], 1); atomicAdd(&bc[e2i], 1);
    }
  }
  __syncthreads();
  if (tid < NE) atomicAdd(&counts[tid], bc[tid]);
}

__global__ void offs_kernel(const int* __restrict__ counts, int* __restrict__ offs) {
  if (threadIdx.x == 0) {
    int run = 0;
#pragma unroll
    for (int e = 0; e < NE; e++) { offs[e] = run; run += (counts[e] + 255) & ~255; }
    offs[NE] = run;
  }
}

__global__ void scatter_kernel(const int* __restrict__ tokE,
                               const int* __restrict__ offs,
                               int* __restrict__ cursor,
                               int* __restrict__ posTok,
                               int* __restrict__ posOf)
{
  const int t = blockIdx.x * 256 + threadIdx.x;
  const int lane = threadIdx.x & 63;
#pragma unroll
  for (int k = 0; k < 2; k++) {
    const int e = tokE[2 * t + k];
    int p = 0;
#pragma unroll
    for (int ei = 0; ei < NE; ei++) {
      unsigned long long mask = __ballot(e == ei);
      if (mask) {
        int leader = __ffsll((unsigned long long)mask) - 1;
        int base = 0;
        if (lane == leader) base = atomicAdd(&cursor[ei], (int)__popcll(mask));
        base = __shfl(base, leader);
        if (e == ei)
          p = offs[ei] + base + (int)__popcll(mask & ((1ull << lane) - 1ull));
      }
    }
    if (p < 0) p = 0;
    if (p >= PADROWS) p = PADROWS - 1;
    posTok[p] = t;
    posOf[2 * t + k] = p;
  }
}

// ============ 256x256 phased GEMM (T2+T3+T4+T5): 8 waves, BK=32, 4 LDS buffers, depth-3 prefetch ============
// LDS swizzle (T2, both-sides involution): LDS row r, 16B slot s holds global chunk s ^ ((r>>1)&3).
// Staged via pre-swizzled global source; read with the same XOR on the slot -> conflict-free quads.
// Sync (T3+T4): raw s_barrier (no vmcnt drain) + counted s_waitcnt vmcnt(8) once per K-tile:
// stage(kt+3) issued during kt; at kt's phase-B wait, drain stage(kt+1) only (leave 8 in flight).

#define STAGE_A(s) { unsigned short* d_ = (unsigned short*)&lds[(s) & 3][0][w * 512]; \
  gload_lds16(gA0 + (size_t)(s) * BK, d_); gload_lds16(gA1 + (size_t)(s) * BK, d_ + 4096); }
#define STAGE_B(s) { unsigned short* d_ = (unsigned short*)&lds[(s) & 3][1][w * 512]; \
  gload_lds16(gB0 + (size_t)(s) * BK, d_); gload_lds16(gB1 + (size_t)(s) * BK, d_ + 4096); }

#define PHASE_MFMA(ACCROW, AV)                                              \
  __builtin_amdgcn_s_barrier();                                             \
  __builtin_amdgcn_s_setprio(1);                                            \
  _Pragma("unroll")                                                         \
  for (int mi = 0; mi < 4; mi++)                                            \
    _Pragma("unroll")                                                       \
    for (int ni = 0; ni < 4; ni++)                                          \
      acc[(ACCROW) + mi][ni] = __builtin_amdgcn_mfma_f32_16x16x32_bf16(     \
          AV[mi], b[ni], acc[(ACCROW) + mi][ni], 0, 0, 0);                  \
  __builtin_amdgcn_s_setprio(0);                                            \
  __builtin_amdgcn_s_barrier();

__global__ __launch_bounds__(512, 2) void gemm1_kernel(
    const unsigned short* __restrict__ Xbf,   // [T][DH] bf16
    const unsigned short* __restrict__ Wgu,   // [NE][NC][DH] bf16 transposed+interleaved
    const int* __restrict__ posTok,
    const int* __restrict__ offs,
    unsigned short* __restrict__ H)           // [PADROWS][FF] bf16
{
  __shared__ __align__(16) unsigned short lds[4][2][8192];   // 128 KiB
  const int NT = DH / BK;                     // 32
  const int n0 = blockIdx.x * 256;
  const int row0 = blockIdx.y * 256;
  if (row0 >= offs[NE]) return;
  int e = 0;
#pragma unroll
  for (int i = 1; i < NE; i++) e += (row0 >= offs[i]) ? 1 : 0;
  const unsigned short* Wb = Wgu + (size_t)e * NC * DH;

  const int tid = threadIdx.x;
  const int lane = tid & 63;
  const int w = tid >> 6;                 // 0..7
  const int wm = w >> 2, wn = w & 3;      // 2 x 4 wave grid
  const int l15 = lane & 15, quad = lane >> 4;

  // staging geometry: issue i covers LDS rows [i*128, i*128+128); thread t -> row t>>2,
  // slot t&3, global chunk pre-swizzled by ^((row>>1)&3) (same for both issues since 128/2%4==0)
  const int srow = tid >> 2;                              // 0..127
  const int sch  = (tid & 3) ^ ((srow >> 1) & 3);
  int t0 = posTok[row0 + srow];       if (t0 < 0) t0 = 0;
  int t1 = posTok[row0 + 128 + srow]; if (t1 < 0) t1 = 0;
  const unsigned short* gA0 = Xbf + (size_t)t0 * DH + sch * 8;
  const unsigned short* gA1 = Xbf + (size_t)t1 * DH + sch * 8;
  const unsigned short* gB0 = Wb + (size_t)(n0 + srow) * DH + sch * 8;
  const unsigned short* gB1 = Wb + (size_t)(n0 + 128 + srow) * DH + sch * 8;

  // reader offsets (elements): row*32 + swizzled_slot*8
  const int slot  = quad ^ ((l15 >> 1) & 3);
  const int aBase = (wm * 128 + l15) * 32 + slot * 8;
  const int bBase = (wn * 64 + l15) * 32 + slot * 8;

  f32x4 acc[8][4];
#pragma unroll
  for (int mi = 0; mi < 8; mi++)
#pragma unroll
    for (int ni = 0; ni < 4; ni++) acc[mi][ni] = (f32x4){0.f, 0.f, 0.f, 0.f};

  // prologue: stage K-tiles 0,1,2; wait oldest (tile 0), leave 8 in flight
  STAGE_A(0); STAGE_B(0);
  STAGE_A(1); STAGE_B(1);
  STAGE_A(2); STAGE_B(2);
  asm volatile("s_waitcnt vmcnt(8)" ::: "memory");
  __builtin_amdgcn_s_barrier();

  for (int kt = 0; kt < NT; ++kt) {
    const unsigned short* LA = &lds[kt & 3][0][0];
    const unsigned short* LB = &lds[kt & 3][1][0];
    // ---- phase A: frags (mi 0..3, all ni) + issue A-stage of kt+3
    bf16x8 a[4], b[4];
#pragma unroll
    for (int i = 0; i < 4; i++) a[i] = *(const bf16x8*)&LA[aBase + i * 512];
#pragma unroll
    for (int i = 0; i < 4; i++) b[i] = *(const bf16x8*)&LB[bBase + i * 512];
    if (kt + 3 < NT) STAGE_A(kt + 3);
    PHASE_MFMA(0, a)
    // ---- phase B: frags (mi 4..7), reuse b; issue B-stage of kt+3; counted vmcnt
    bf16x8 a2[4];
#pragma unroll
    for (int i = 0; i < 4; i++) a2[i] = *(const bf16x8*)&LA[aBase + (4 + i) * 512];
    if (kt + 3 < NT) STAGE_B(kt + 3);
    if (kt + 3 < NT)       { asm volatile("s_waitcnt vmcnt(8)" ::: "memory"); }
    else if (kt + 3 == NT) { asm volatile("s_waitcnt vmcnt(4)" ::: "memory"); }
    else if (kt + 1 < NT)  { asm volatile("s_waitcnt vmcnt(0)" ::: "memory"); }
    PHASE_MFMA(4, a2)
  }

  // epilogue: silu(gate)*up, interleaved column pairs
  const int rowb = row0 + wm * 128;
#pragma unroll
  for (int mi = 0; mi < 8; mi++) {
#pragma unroll
    for (int p = 0; p < 2; p++) {
      f32x4 g = acc[mi][2 * p], u = acc[mi][2 * p + 1];
      int f = (n0 >> 1) + wn * 32 + p * 16 + l15;
#pragma unroll
      for (int r = 0; r < 4; r++) {
        int row = rowb + mi * 16 + quad * 4 + r;
        float gv = g[r];
        float hv = (gv / (1.f + __expf(-gv))) * u[r];
        H[(size_t)row * FF + f] = f2bf(hv);
      }
    }
  }
}

__global__ __launch_bounds__(512, 2) void gemm2_kernel(
    const unsigned short* __restrict__ H,     // [PADROWS][FF] bf16
    const unsigned short* __restrict__ Wdn,   // [NE][DH][FF] bf16 transposed
    const int* __restrict__ offs,
    unsigned short* __restrict__ Y)           // [PADROWS][DH] bf16
{
  __shared__ __align__(16) unsigned short lds[4][2][8192];   // 128 KiB
  const int NT = FF / BK;                     // 64
  const int n0 = blockIdx.x * 256;
  const int row0 = blockIdx.y * 256;
  if (row0 >= offs[NE]) return;
  int e = 0;
#pragma unroll
  for (int i = 1; i < NE; i++) e += (row0 >= offs[i]) ? 1 : 0;
  const unsigned short* Wb = Wdn + (size_t)e * DH * FF;

  const int tid = threadIdx.x;
  const int lane = tid & 63;
  const int w = tid >> 6;
  const int wm = w >> 2, wn = w & 3;
  const int l15 = lane & 15, quad = lane >> 4;

  const int srow = tid >> 2;
  const int sch  = (tid & 3) ^ ((srow >> 1) & 3);
  const unsigned short* gA0 = H + (size_t)(row0 + srow) * FF + sch * 8;
  const unsigned short* gA1 = H + (size_t)(row0 + 128 + srow) * FF + sch * 8;
  const unsigned short* gB0 = Wb + (size_t)(n0 + srow) * FF + sch * 8;
  const unsigned short* gB1 = Wb + (size_t)(n0 + 128 + srow) * FF + sch * 8;

  const int slot  = quad ^ ((l15 >> 1) & 3);
  const int aBase = (wm * 128 + l15) * 32 + slot * 8;
  const int bBase = (wn * 64 + l15) * 32 + slot * 8;

  f32x4 acc[8][4];
#pragma unroll
  for (int mi = 0; mi < 8; mi++)
#pragma unroll
    for (int ni = 0; ni < 4; ni++) acc[mi][ni] = (f32x4){0.f, 0.f, 0.f, 0.f};

  STAGE_A(0); STAGE_B(0);
  STAGE_A(1); STAGE_B(1);
  STAGE_A(2); STAGE_B(2);
  asm volatile("s_waitcnt vmcnt(8)" ::: "memory");
  __builtin_amdgcn_s_barrier();

  for (int kt = 0; kt < NT; ++kt) {
    const unsigned short* LA = &lds[kt & 3][0][0];
    const unsigned short* LB = &lds[kt & 3][1][0];
    bf16x8 a[4], b[4];
#pragma unroll
    for (int i = 0; i < 4; i++) a[i] = *(const bf16x8*)&LA[aBase + i * 512];
#pragma unroll
    for (int i = 0; i < 4; i++) b[i] = *(const bf16x8*)&LB[bBase + i * 512];
    if (kt + 3 < NT) STAGE_A(kt + 3);
    PHASE_MFMA(0, a)
    bf16x8 a2[4];
#pragma unroll
    for (int i = 0; i < 4; i++) a2[i] = *(const bf16x8*)&LA[aBase + (4 + i) * 512];
    if (kt + 3 < NT) STAGE_B(kt + 3);
    if (kt + 3 < NT)       { asm volatile("s_waitcnt vmcnt(8)" ::: "memory"); }
    else if (kt + 3 == NT) { asm volatile("s_waitcnt vmcnt(4)" ::: "memory"); }
    else if (kt + 1 < NT)  { asm volatile("s_waitcnt vmcnt(0)" ::: "memory"); }
    PHASE_MFMA(4, a2)
  }

#pragma unroll
  for (int mi = 0; mi < 8; mi++)
#pragma unroll
    for (int ni = 0; ni < 4; ni++) {
      int col = n0 + wn * 64 + ni * 16 + l15;
#pragma unroll
      for (int r = 0; r < 4; r++) {
        int row = row0 + wm * 128 + mi * 16 + quad * 4 + r;
        Y[(size_t)row * DH + col] = f2bf(acc[mi][ni][r]);
      }
    }
}

// ---------------- combine: out[t] = w0*Y[p0] + w1*Y[p1]  (bf16 Y -> fp32 out) ----------------
__global__ void combine_kernel(const unsigned short* __restrict__ Y,
                               const int* __restrict__ posOf,
                               const float* __restrict__ tokW,
                               float* __restrict__ out)
{
  int idx = blockIdx.x * 256 + threadIdx.x;
  int t = idx >> 7;
  int c = (idx & 127) * 8;
  int p0 = posOf[2 * t], p1 = posOf[2 * t + 1];
  float w0 = tokW[2 * t], w1 = tokW[2 * t + 1];
  const uint4 a = *(const uint4*)&Y[(size_t)p0 * DH + c];
  const uint4 b = *(const uint4*)&Y[(size_t)p1 * DH + c];
  const unsigned* ap = (const unsigned*)&a;
  const unsigned* bp = (const unsigned*)&b;
  float4 o0, o1;
#pragma unroll
  for (int i = 0; i < 4; i++) {
    float a0 = bf2f((unsigned short)(ap[i] & 0xffff)), a1 = bf2f((unsigned short)(ap[i] >> 16));
    float b0 = bf2f((unsigned short)(bp[i] & 0xffff)), b1 = bf2f((unsigned short)(bp[i] >> 16));
    float r0 = w0 * a0 + w1 * b0;
    float r1 = w0 * a1 + w1 * b1;
    if (i < 2) { ((float*)&o0)[2 * i] = r0; ((float*)&o0)[2 * i + 1] = r1; }
    else       { ((float*)&o1)[2 * (i - 2)] = r0; ((float*)&o1)[2 * (i - 2) + 1] = r1; }
  }
  *(float4*)&out[(size_t)t * DH + c]     = o0;
  *(float4*)&out[(size_t)t * DH + c + 4] = o1;
}

extern "C" void kernel_launch(void* const* d_in, const int* in_sizes, int n_in,
                              void* d_out, int out_size, void* d_ws, size_t ws_size,
                              hipStream_t stream)
{
  const float* X   = (const float*)d_in[0];
  const float* GW  = (const float*)d_in[1];
  const float* GLD = (const float*)d_in[2];
  const float* GUP = (const float*)d_in[3];
  const float* DNP = (const float*)d_in[4];
  const float* GUA = (const float*)d_in[5];
  const float* GUB = (const float*)d_in[6];
  const float* DNA = (const float*)d_in[7];
  const float* DNB = (const float*)d_in[8];
  float* OUT = (float*)d_out;

  char* p = (char*)d_ws;
  unsigned short* Wguf = (unsigned short*)p; p += (size_t)NE * NC * DH * 2;   // 64 MiB
  unsigned short* Wdnf = (unsigned short*)p; p += (size_t)NE * DH * FF * 2;   // 32 MiB
  unsigned short* H    = (unsigned short*)p; p += (size_t)PADROWS * FF * 2;   // 136 MiB
  unsigned short* Y    = (unsigned short*)p; p += (size_t)PADROWS * DH * 2;   // 68 MiB
  int*   posTok = (int*)p;   p += (size_t)PADROWS * 4;
  int*   posOf  = (int*)p;   p += (size_t)T_TOK * 2 * 4;
  int*   tokE   = (int*)p;   p += (size_t)T_TOK * 2 * 4;
  float* tokW   = (float*)p; p += (size_t)T_TOK * 2 * 4;
  int*   counts = (int*)p;   p += 32;
  int*   cursor = (int*)p;   p += 32;
  int*   offs   = (int*)p;   p += 64;
  if ((size_t)(p - (char*)d_ws) > ws_size) return;  // workspace too small

  // Xbf (32 MiB) aliases Y (68 MiB): Xbf written by route, read by gemm1;
  // Y written by gemm2 (after gemm1) and read by combine. Same-stream serial.
  unsigned short* Xbf = Y;

  hipMemsetAsync(counts, 0, 32 + 32 + 64, stream);   // counts+cursor+offs
  hipMemsetAsync(posTok, 0xFF, (size_t)PADROWS * 4, stream);

  fold_gu_kernel<<<dim3(NE, DH / 64, NC / 64), 256, 0, stream>>>(GUP, GUA, GUB, Wguf);
  fold_dn_kernel<<<dim3(NE, FF / 64, DH / 64), 256, 0, stream>>>(DNP, DNA, DNB, Wdnf);
  route_kernel<<<T_TOK / 32, 256, 0, stream>>>(X, GW, GLD, Xbf, tokE, tokW, counts);
  offs_kernel<<<1, 64, 0, stream>>>(counts, offs);
  scatter_kernel<<<T_TOK / 256, 256, 0, stream>>>(tokE, offs, cursor, posTok, posOf);
  gemm1_kernel<<<dim3(NC / 256, PADROWS / 256), 512, 0, stream>>>(Xbf, Wguf, posTok, offs, H);
  gemm2_kernel<<<dim3(DH / 256, PADROWS / 256), 512, 0, stream>>>(H, Wdnf, offs, Y);
  combine_kernel<<<(T_TOK * DH / 8) / 256, 256, 0, stream>>>(Y, posOf, tokW, OUT);
}